// Round 1
// baseline (330.099 us; speedup 1.0000x reference)
//
#include <hip/hip_runtime.h>
#include <cstddef>

// Problem constants (fixed by the module source)
namespace {
constexpr int B  = 2;
constexpr int Z  = 200;
constexpr int X  = 200;
constexpr int C  = 128;
constexpr int H  = 4;
constexpr int P  = 8;
constexpr int N  = Z * X;          // 40000
constexpr int BN = B * N;          // 80000
constexpr int PC = C + H*P*2 + H*P; // 224 combined projection cols
constexpr int OFF0 = C;            // 128: start of offset cols
constexpr int ATT0 = C + H*P*2;    // 192: start of attn-logit cols
}

// ---------------------------------------------------------------------------
// Fold the two output projections: w12[k][c] = sum_j Wout1[k][j]*Wout2[j][c]
// Row 128 holds the fused bias: b12[c] = bout1 @ Wout2 + bout2.
// ---------------------------------------------------------------------------
__global__ void vsa_k_w12(const float* __restrict__ Wout1, const float* __restrict__ bout1,
                          const float* __restrict__ Wout2, const float* __restrict__ bout2,
                          float* __restrict__ w12) {
    int gid = blockIdx.x * 256 + threadIdx.x;
    if (gid >= 129 * 128) return;
    int k = gid >> 7;   // 0..128
    int c = gid & 127;
    const float* arow = (k < 128) ? (Wout1 + (size_t)k * 128) : bout1;
    float acc = (k < 128) ? 0.f : bout2[c];
    for (int j = 0; j < 128; ++j)
        acc = fmaf(arow[j], Wout2[(size_t)j * 128 + c], acc);
    w12[gid] = acc;
}

// ---------------------------------------------------------------------------
// Fused projection GEMM: proj[row][0..223] = Q[row] @ [Wv|Woff|Wattn] + bias
// M=80000, N=224, K=128. Block = 256 threads, tile 64 rows x 224 cols, BK=32.
// Thread (tr=tid>>3, tc=tid&7) owns rows {2tr,2tr+1} x cols [28tc, 28tc+28).
// ---------------------------------------------------------------------------
__global__ __launch_bounds__(256) void vsa_k_proj(
        const float* __restrict__ Q,
        const float* __restrict__ Wv,   const float* __restrict__ bv,
        const float* __restrict__ Woff, const float* __restrict__ boff,
        const float* __restrict__ Wattn,const float* __restrict__ battn,
        float* __restrict__ proj) {
    __shared__ float As[32][66];    // [k][row], pitch 66 keeps float2 reads aligned
    __shared__ float Ws[32][224];   // [k][col]
    __shared__ float bias[224];

    const int tid  = threadIdx.x;
    const int row0 = blockIdx.x * 64;

    if (tid < 224) {
        float bb;
        if (tid < 128)      bb = bv[tid];
        else if (tid < 192) bb = boff[tid - 128];
        else                bb = battn[tid - 192];
        bias[tid] = bb;
    }

    const int tr = tid >> 3;   // 0..31
    const int tc = tid & 7;    // 0..7

    float acc[2][28];
    #pragma unroll
    for (int r = 0; r < 2; ++r)
        #pragma unroll
        for (int c = 0; c < 28; ++c) acc[r][c] = 0.f;

    for (int k0 = 0; k0 < 128; k0 += 32) {
        // Stage A tile (64 rows x 32 k), transposed into LDS
        #pragma unroll
        for (int i = 0; i < 2; ++i) {
            int li = tid + i * 256;             // 0..511
            int r  = li >> 3, kc = li & 7;
            float4 a4 = *(const float4*)(Q + (size_t)(row0 + r) * 128 + k0 + kc * 4);
            As[kc*4+0][r] = a4.x; As[kc*4+1][r] = a4.y;
            As[kc*4+2][r] = a4.z; As[kc*4+3][r] = a4.w;
        }
        // Stage W tile (32 k x 224 cols) from the three weight matrices
        #pragma unroll
        for (int i = 0; i < 7; ++i) {
            int li = tid + i * 256;             // 0..1791
            int kk = li / 56;
            int cc = (li - kk * 56) * 4;        // 0..220 step 4
            const float* src;
            if (cc < 128)      src = Wv    + (size_t)(k0 + kk) * 128 + cc;
            else if (cc < 192) src = Woff  + (size_t)(k0 + kk) * 64  + (cc - 128);
            else               src = Wattn + (size_t)(k0 + kk) * 32  + (cc - 192);
            *(float4*)&Ws[kk][cc] = *(const float4*)src;
        }
        __syncthreads();

        #pragma unroll 4
        for (int kk = 0; kk < 32; ++kk) {
            float2 a = *(const float2*)&As[kk][tr * 2];
            #pragma unroll
            for (int j = 0; j < 7; ++j) {
                float4 wv = *(const float4*)&Ws[kk][tc * 28 + j * 4];
                acc[0][j*4+0] = fmaf(a.x, wv.x, acc[0][j*4+0]);
                acc[0][j*4+1] = fmaf(a.x, wv.y, acc[0][j*4+1]);
                acc[0][j*4+2] = fmaf(a.x, wv.z, acc[0][j*4+2]);
                acc[0][j*4+3] = fmaf(a.x, wv.w, acc[0][j*4+3]);
                acc[1][j*4+0] = fmaf(a.y, wv.x, acc[1][j*4+0]);
                acc[1][j*4+1] = fmaf(a.y, wv.y, acc[1][j*4+1]);
                acc[1][j*4+2] = fmaf(a.y, wv.z, acc[1][j*4+2]);
                acc[1][j*4+3] = fmaf(a.y, wv.w, acc[1][j*4+3]);
            }
        }
        __syncthreads();
    }

    #pragma unroll
    for (int r = 0; r < 2; ++r) {
        int row = row0 + tr * 2 + r;
        float* dst = proj + (size_t)row * PC + tc * 28;
        #pragma unroll
        for (int j = 0; j < 7; ++j) {
            float4 o;
            o.x = acc[r][j*4+0] + bias[tc*28 + j*4+0];
            o.y = acc[r][j*4+1] + bias[tc*28 + j*4+1];
            o.z = acc[r][j*4+2] + bias[tc*28 + j*4+2];
            o.w = acc[r][j*4+3] + bias[tc*28 + j*4+3];
            *(float4*)(dst + j * 4) = o;
        }
    }
}

// ---------------------------------------------------------------------------
// Deformable sampling + softmax + weighted reduce.
// One wave per (b,h,n); lane = (pp, d): pp=lane>>5 handles points {2i+pp},
// d=lane&31 is the head-dim element (32 consecutive floats -> coalesced 128B).
// Wave order iterates z fastest (sampling is transposed) for L2 locality.
// ---------------------------------------------------------------------------
__global__ __launch_bounds__(256) void vsa_k_sample(const float* __restrict__ proj,
                                                    float* __restrict__ tmp) {
    const int w    = blockIdx.x * 4 + (threadIdx.x >> 6);
    const int lane = threadIdx.x & 63;
    const int d    = lane & 31;
    const int pp   = lane >> 5;

    const int b   = w / (H * N);
    int rem       = w - b * (H * N);
    const int h   = rem / N;
    int pix       = rem - h * N;
    const int x   = pix / Z;        // x_j (slow)
    const int z   = pix - x * Z;    // z_i (fast -> adjacent value rows)
    const int n   = z * X + x;
    const size_t bn = (size_t)b * N + n;

    const float* prow = proj + bn * PC;

    // softmax over the 8 points of this head (redundant per lane; L1 broadcast)
    float lg[P];
    float m = -1e30f;
    #pragma unroll
    for (int p = 0; p < P; ++p) { lg[p] = prow[ATT0 + h * P + p]; m = fmaxf(m, lg[p]); }
    float s = 0.f;
    #pragma unroll
    for (int p = 0; p < P; ++p) { lg[p] = __expf(lg[p] - m); s += lg[p]; }
    const float inv = 1.0f / s;

    const float* vbase = proj + (size_t)b * N * PC + h * 32 + d;

    float acc = 0.f;
    #pragma unroll
    for (int it = 0; it < 4; ++it) {
        const int p = it * 2 + pp;
        const float ox = prow[OFF0 + (h * P + p) * 2 + 0];
        const float oy = prow[OFF0 + (h * P + p) * 2 + 1];
        // ix = z + off0, iy = x + off1 (coordinate algebra collapses)
        const float ixf = (float)z + ox;
        const float iyf = (float)x + oy;
        const float x0f = floorf(ixf), y0f = floorf(iyf);
        const float lx = ixf - x0f, ly = iyf - y0f;
        const int x0 = (int)x0f, y0 = (int)y0f;
        const int x1 = x0 + 1,  y1 = y0 + 1;
        const int xc0 = min(max(x0, 0), X - 1), xc1 = min(max(x1, 0), X - 1);
        const int yc0 = min(max(y0, 0), Z - 1), yc1 = min(max(y1, 0), Z - 1);
        const float vx0 = (x0 >= 0 && x0 < X) ? 1.f : 0.f;
        const float vx1 = (x1 >= 0 && x1 < X) ? 1.f : 0.f;
        const float vy0 = (y0 >= 0 && y0 < Z) ? 1.f : 0.f;
        const float vy1 = (y1 >= 0 && y1 < Z) ? 1.f : 0.f;

        const float v00 = vbase[(size_t)(yc0 * X + xc0) * PC];
        const float v10 = vbase[(size_t)(yc0 * X + xc1) * PC];
        const float v01 = vbase[(size_t)(yc1 * X + xc0) * PC];
        const float v11 = vbase[(size_t)(yc1 * X + xc1) * PC];

        const float w00 = (1.f - lx) * (1.f - ly) * vx0 * vy0;
        const float w10 = lx * (1.f - ly) * vx1 * vy0;
        const float w01 = (1.f - lx) * ly * vx0 * vy1;
        const float w11 = lx * ly * vx1 * vy1;

        const float pv = w00 * v00 + w10 * v10 + w01 * v01 + w11 * v11;
        acc = fmaf(lg[p] * inv, pv, acc);
    }
    acc += __shfl_xor(acc, 32);
    if (pp == 0) tmp[bn * C + h * 32 + d] = acc;
}

// ---------------------------------------------------------------------------
// Output GEMM + residual: out = tmp @ W12 + b12 + Q.
// M=80000, N=128, K=128. Same tiling as vsa_k_proj; thread owns cols
// {4tc+32j : j=0..3} (strided to stay LDS-bank-conflict-free).
// ---------------------------------------------------------------------------
__global__ __launch_bounds__(256) void vsa_k_out(const float* __restrict__ tmpA,
                                                 const float* __restrict__ w12,
                                                 const float* __restrict__ Q,
                                                 float* __restrict__ out) {
    __shared__ float As[32][66];
    __shared__ float Ws[32][128];
    __shared__ float bias[128];

    const int tid  = threadIdx.x;
    const int row0 = blockIdx.x * 64;
    if (tid < 128) bias[tid] = w12[128 * 128 + tid];

    const int tr = tid >> 3;
    const int tc = tid & 7;

    float acc[2][16];
    #pragma unroll
    for (int r = 0; r < 2; ++r)
        #pragma unroll
        for (int c = 0; c < 16; ++c) acc[r][c] = 0.f;

    for (int k0 = 0; k0 < 128; k0 += 32) {
        #pragma unroll
        for (int i = 0; i < 2; ++i) {
            int li = tid + i * 256;
            int r  = li >> 3, kc = li & 7;
            float4 a4 = *(const float4*)(tmpA + (size_t)(row0 + r) * 128 + k0 + kc * 4);
            As[kc*4+0][r] = a4.x; As[kc*4+1][r] = a4.y;
            As[kc*4+2][r] = a4.z; As[kc*4+3][r] = a4.w;
        }
        #pragma unroll
        for (int i = 0; i < 4; ++i) {
            int li = tid + i * 256;            // 0..1023
            int kk = li >> 5, cc = (li & 31) * 4;
            *(float4*)&Ws[kk][cc] = *(const float4*)(w12 + (size_t)(k0 + kk) * 128 + cc);
        }
        __syncthreads();

        #pragma unroll 4
        for (int kk = 0; kk < 32; ++kk) {
            float2 a = *(const float2*)&As[kk][tr * 2];
            #pragma unroll
            for (int j = 0; j < 4; ++j) {
                float4 wv = *(const float4*)&Ws[kk][tc * 4 + j * 32];
                acc[0][j*4+0] = fmaf(a.x, wv.x, acc[0][j*4+0]);
                acc[0][j*4+1] = fmaf(a.x, wv.y, acc[0][j*4+1]);
                acc[0][j*4+2] = fmaf(a.x, wv.z, acc[0][j*4+2]);
                acc[0][j*4+3] = fmaf(a.x, wv.w, acc[0][j*4+3]);
                acc[1][j*4+0] = fmaf(a.y, wv.x, acc[1][j*4+0]);
                acc[1][j*4+1] = fmaf(a.y, wv.y, acc[1][j*4+1]);
                acc[1][j*4+2] = fmaf(a.y, wv.z, acc[1][j*4+2]);
                acc[1][j*4+3] = fmaf(a.y, wv.w, acc[1][j*4+3]);
            }
        }
        __syncthreads();
    }

    #pragma unroll
    for (int r = 0; r < 2; ++r) {
        const int row = row0 + tr * 2 + r;
        #pragma unroll
        for (int j = 0; j < 4; ++j) {
            const int cbase = tc * 4 + j * 32;
            float4 q4 = *(const float4*)(Q + (size_t)row * 128 + cbase);
            float4 o;
            o.x = acc[r][j*4+0] + bias[cbase + 0] + q4.x;
            o.y = acc[r][j*4+1] + bias[cbase + 1] + q4.y;
            o.z = acc[r][j*4+2] + bias[cbase + 2] + q4.z;
            o.w = acc[r][j*4+3] + bias[cbase + 3] + q4.w;
            *(float4*)(out + (size_t)row * 128 + cbase) = o;
        }
    }
}

// ---------------------------------------------------------------------------
extern "C" void kernel_launch(void* const* d_in, const int* in_sizes, int n_in,
                              void* d_out, int out_size, void* d_ws, size_t ws_size,
                              hipStream_t stream) {
    const float* Q     = (const float*)d_in[0];
    const float* Wv    = (const float*)d_in[1];
    const float* bv    = (const float*)d_in[2];
    const float* Woff  = (const float*)d_in[3];
    const float* boff  = (const float*)d_in[4];
    const float* Wattn = (const float*)d_in[5];
    const float* battn = (const float*)d_in[6];
    const float* Wout1 = (const float*)d_in[7];
    const float* bout1 = (const float*)d_in[8];
    const float* Wout2 = (const float*)d_in[9];
    const float* bout2 = (const float*)d_in[10];
    float* out = (float*)d_out;

    // Workspace layout (f32): proj[BN][224] | tmp[BN][128] | w12[129][128]
    float* proj = (float*)d_ws;
    float* tmp  = proj + (size_t)BN * PC;
    float* w12  = tmp + (size_t)BN * C;

    vsa_k_w12<<<(129 * 128 + 255) / 256, 256, 0, stream>>>(Wout1, bout1, Wout2, bout2, w12);
    vsa_k_proj<<<BN / 64, 256, 0, stream>>>(Q, Wv, bv, Woff, boff, Wattn, battn, proj);
    vsa_k_sample<<<(B * N * H) / 4, 256, 0, stream>>>(proj, tmp);
    vsa_k_out<<<BN / 64, 256, 0, stream>>>(tmp, w12, Q, out);
}

// Round 2
// 144.016 us; speedup vs baseline: 2.2921x; 2.2921x over previous
//
#include <hip/hip_runtime.h>
#include <hip/hip_bf16.h>
#include <cstddef>

namespace {
constexpr int B  = 2;
constexpr int Z  = 200;
constexpr int X  = 200;
constexpr int C  = 128;
constexpr int H  = 4;
constexpr int P  = 8;
constexpr int N  = Z * X;       // 40000
constexpr int BN = B * N;       // 80000
constexpr int SC = 96;          // proj_s cols (64 offset + 32 attn-logit)
constexpr int NF_P = 14;        // 224/16 output fragments (proj GEMM)
constexpr int NF_O = 8;         // 128/16 output fragments (out GEMM)
constexpr int KS   = 4;         // 128/32 K-steps

typedef __attribute__((ext_vector_type(8))) short short8;
typedef __attribute__((ext_vector_type(4))) float f32x4;

__device__ inline ushort f2bf(float x) {
    __hip_bfloat16 h = __float2bfloat16(x);
    return *reinterpret_cast<ushort*>(&h);
}
__device__ inline float bflo(unsigned u) { return __uint_as_float(u << 16); }
__device__ inline float bfhi(unsigned u) { return __uint_as_float(u & 0xffff0000u); }
__device__ inline unsigned packbf(float a, float b) {
    return (unsigned)f2bf(a) | ((unsigned)f2bf(b) << 16);
}
}

// ---------------------------------------------------------------------------
// Prep: pack weights into MFMA B-fragment order wt[ks][f][lane][8 bf16],
// where elem e of lane l in frag f at kstep ks is W[k][n],
// k = ks*32 + (l>>4)*8 + e, n = f*16 + (l&15).
// Also folds W12 = Wout1@Wout2 (computed inline), biasp[224], b12[128].
// ---------------------------------------------------------------------------
__global__ __launch_bounds__(256) void vsa_k_prep(
    const float* __restrict__ Wv,    const float* __restrict__ bv,
    const float* __restrict__ Woff,  const float* __restrict__ boff,
    const float* __restrict__ Wattn, const float* __restrict__ battn,
    const float* __restrict__ Wout1, const float* __restrict__ bout1,
    const float* __restrict__ Wout2, const float* __restrict__ bout2,
    ushort* __restrict__ wtp, ushort* __restrict__ wtp2,
    float* __restrict__ biasp, float* __restrict__ bias2)
{
    const int u = blockIdx.x * 256 + threadIdx.x;
    constexpr int NP = KS * NF_P * 64;   // 3584
    constexpr int NO = KS * NF_O * 64;   // 2048

    if (u < NP) {
        int ks  = u / (NF_P * 64);
        int rem = u - ks * (NF_P * 64);
        int f = rem >> 6, l = rem & 63;
        int n  = f * 16 + (l & 15);
        int kb = ks * 32 + (l >> 4) * 8;
        float v[8];
        #pragma unroll
        for (int e = 0; e < 8; ++e) {
            int k = kb + e;
            if (n < 128)      v[e] = Wv[k * 128 + n];
            else if (n < 192) v[e] = Woff[k * 64 + (n - 128)];
            else              v[e] = Wattn[k * 32 + (n - 192)];
        }
        unsigned* dst = (unsigned*)(wtp + (size_t)u * 8);
        #pragma unroll
        for (int i = 0; i < 4; ++i) dst[i] = packbf(v[2*i], v[2*i+1]);
    } else if (u < NP + NO) {
        int t   = u - NP;
        int ks  = t / (NF_O * 64);
        int rem = t - ks * (NF_O * 64);
        int f = rem >> 6, l = rem & 63;
        int n  = f * 16 + (l & 15);
        int kb = ks * 32 + (l >> 4) * 8;
        float acc[8] = {0,0,0,0,0,0,0,0};
        for (int j = 0; j < 128; ++j) {
            float w2 = Wout2[j * 128 + n];
            #pragma unroll
            for (int e = 0; e < 8; ++e)
                acc[e] = fmaf(Wout1[(kb + e) * 128 + j], w2, acc[e]);
        }
        unsigned* dst = (unsigned*)(wtp2 + (size_t)t * 8);
        #pragma unroll
        for (int i = 0; i < 4; ++i) dst[i] = packbf(acc[2*i], acc[2*i+1]);
    } else if (u < NP + NO + 224) {
        int c = u - NP - NO;
        float bb;
        if (c < 128)      bb = bv[c];
        else if (c < 192) bb = boff[c - 128];
        else              bb = battn[c - 192];
        biasp[c] = bb;
    } else if (u < NP + NO + 224 + 128) {
        int c = u - NP - NO - 224;
        float acc = bout2[c];
        for (int j = 0; j < 128; ++j)
            acc = fmaf(bout1[j], Wout2[j * 128 + c], acc);
        bias2[c] = acc;
    }
}

// ---------------------------------------------------------------------------
// Fused projection GEMM (MFMA, no LDS): proj = Q @ [Wv|Woff|Wattn] + bias.
// One wave per 16 rows. A-frag: m=lane&15, k=(lane>>4)*8+e (8 contiguous f32
// from Q, converted inline). B-frags: coalesced 16B/lane from packed wtp.
// D: col=lane&15, row=(lane>>4)*4+reg.
// Value cols (0..127) stored bf16 to proj_v; offset/logit cols f32 to proj_s.
// ---------------------------------------------------------------------------
__global__ __launch_bounds__(256) void vsa_k_proj(
    const float* __restrict__ Q, const ushort* __restrict__ wtp,
    const float* __restrict__ biasp,
    ushort* __restrict__ proj_v, float* __restrict__ proj_s)
{
    const int lane = threadIdx.x & 63;
    const int wave = blockIdx.x * 4 + (threadIdx.x >> 6);
    const int row0 = wave * 16;
    const int m  = lane & 15;
    const int kg = lane >> 4;

    const float* qp = Q + (size_t)(row0 + m) * 128 + kg * 8;

    f32x4 acc[NF_P];
    #pragma unroll
    for (int f = 0; f < NF_P; ++f) acc[f] = (f32x4){0.f, 0.f, 0.f, 0.f};

    #pragma unroll
    for (int ks = 0; ks < KS; ++ks) {
        float4 a0 = *(const float4*)(qp + ks * 32);
        float4 a1 = *(const float4*)(qp + ks * 32 + 4);
        short8 af;
        af[0] = (short)f2bf(a0.x); af[1] = (short)f2bf(a0.y);
        af[2] = (short)f2bf(a0.z); af[3] = (short)f2bf(a0.w);
        af[4] = (short)f2bf(a1.x); af[5] = (short)f2bf(a1.y);
        af[6] = (short)f2bf(a1.z); af[7] = (short)f2bf(a1.w);
        const short8* wrow = (const short8*)wtp + ks * NF_P * 64 + lane;
        #pragma unroll
        for (int f = 0; f < NF_P; ++f)
            acc[f] = __builtin_amdgcn_mfma_f32_16x16x32_bf16(af, wrow[f * 64], acc[f], 0, 0, 0);
    }

    #pragma unroll
    for (int f = 0; f < NF_P; ++f) {
        const int col = f * 16 + m;
        const float bb = biasp[col];
        #pragma unroll
        for (int r = 0; r < 4; ++r) {
            const int row = row0 + kg * 4 + r;
            const float v = acc[f][r] + bb;
            if (col < 128) proj_v[(size_t)row * 128 + col] = f2bf(v);
            else           proj_s[(size_t)row * SC + (col - 128)] = v;
        }
    }
}

// ---------------------------------------------------------------------------
// Deformable sampling + softmax + weighted reduce.
// One wave per (b,h,n): lane = p*8 + d4 (p = point, d4 = 4 head-dim elems).
// Softmax over p via xor-shuffles (masks 8/16/32); bf16 corner gathers
// (dwordx2 = 4 values/lane); xor-butterfly reduce over p; bf16 store.
// z iterates fastest (reference sampling is transposed) for L2 locality.
// ---------------------------------------------------------------------------
__global__ __launch_bounds__(256) void vsa_k_sample(
    const ushort* __restrict__ proj_v, const float* __restrict__ proj_s,
    ushort* __restrict__ tmp)
{
    const int w    = blockIdx.x * 4 + (threadIdx.x >> 6);
    const int lane = threadIdx.x & 63;
    const int p  = lane >> 3;
    const int d4 = lane & 7;

    const int b = w / (H * N);
    int rem     = w - b * (H * N);
    const int h = rem / N;
    int pix     = rem - h * N;
    const int x = pix / Z;          // slow
    const int z = pix - x * Z;      // fast -> adjacent value rows
    const size_t bn = (size_t)b * N + z * X + x;

    const float* srow = proj_s + bn * SC;

    // softmax over the 8 points (p lives in lane bits 3..5)
    float lg = srow[64 + h * 8 + p];
    float mx = lg;
    mx = fmaxf(mx, __shfl_xor(mx, 8));
    mx = fmaxf(mx, __shfl_xor(mx, 16));
    mx = fmaxf(mx, __shfl_xor(mx, 32));
    float ex = __expf(lg - mx);
    float s = ex;
    s += __shfl_xor(s, 8); s += __shfl_xor(s, 16); s += __shfl_xor(s, 32);
    const float wp = ex / s;

    const float2 off = *(const float2*)(srow + (h * 8 + p) * 2);
    const float ixf = (float)z + off.x;
    const float iyf = (float)x + off.y;
    const float x0f = floorf(ixf), y0f = floorf(iyf);
    const float lx = ixf - x0f, ly = iyf - y0f;
    const int x0 = (int)x0f, y0 = (int)y0f;
    const int x1 = x0 + 1,  y1 = y0 + 1;
    const int xc0 = min(max(x0, 0), X - 1), xc1 = min(max(x1, 0), X - 1);
    const int yc0 = min(max(y0, 0), Z - 1), yc1 = min(max(y1, 0), Z - 1);
    const float vx0 = (x0 >= 0 && x0 < X) ? 1.f : 0.f;
    const float vx1 = (x1 >= 0 && x1 < X) ? 1.f : 0.f;
    const float vy0 = (y0 >= 0 && y0 < Z) ? 1.f : 0.f;
    const float vy1 = (y1 >= 0 && y1 < Z) ? 1.f : 0.f;

    const float w00 = (1.f - lx) * (1.f - ly) * vx0 * vy0 * wp;
    const float w10 = lx * (1.f - ly) * vx1 * vy0 * wp;
    const float w01 = (1.f - lx) * ly * vx0 * vy1 * wp;
    const float w11 = lx * ly * vx1 * vy1 * wp;

    const ushort* vb = proj_v + (size_t)b * N * 128 + h * 32 + d4 * 4;
    const uint2 c00 = *(const uint2*)(vb + (size_t)(yc0 * X + xc0) * 128);
    const uint2 c10 = *(const uint2*)(vb + (size_t)(yc0 * X + xc1) * 128);
    const uint2 c01 = *(const uint2*)(vb + (size_t)(yc1 * X + xc0) * 128);
    const uint2 c11 = *(const uint2*)(vb + (size_t)(yc1 * X + xc1) * 128);

    float a0 = w00 * bflo(c00.x) + w10 * bflo(c10.x) + w01 * bflo(c01.x) + w11 * bflo(c11.x);
    float a1 = w00 * bfhi(c00.x) + w10 * bfhi(c10.x) + w01 * bfhi(c01.x) + w11 * bfhi(c11.x);
    float a2 = w00 * bflo(c00.y) + w10 * bflo(c10.y) + w01 * bflo(c01.y) + w11 * bflo(c11.y);
    float a3 = w00 * bfhi(c00.y) + w10 * bfhi(c10.y) + w01 * bfhi(c01.y) + w11 * bfhi(c11.y);

    a0 += __shfl_xor(a0, 8);  a1 += __shfl_xor(a1, 8);
    a2 += __shfl_xor(a2, 8);  a3 += __shfl_xor(a3, 8);
    a0 += __shfl_xor(a0, 16); a1 += __shfl_xor(a1, 16);
    a2 += __shfl_xor(a2, 16); a3 += __shfl_xor(a3, 16);
    a0 += __shfl_xor(a0, 32); a1 += __shfl_xor(a1, 32);
    a2 += __shfl_xor(a2, 32); a3 += __shfl_xor(a3, 32);

    if (lane < 8) {
        uint2 o;
        o.x = packbf(a0, a1);
        o.y = packbf(a2, a3);
        *(uint2*)(tmp + bn * 128 + h * 32 + d4 * 4) = o;
    }
}

// ---------------------------------------------------------------------------
// Output GEMM (MFMA, no LDS) + residual: out = tmp @ W12 + b12 + Q.
// Same fragment scheme as vsa_k_proj; A read directly as bf16 from tmp.
// ---------------------------------------------------------------------------
__global__ __launch_bounds__(256) void vsa_k_out(
    const ushort* __restrict__ tmp, const ushort* __restrict__ wtp2,
    const float* __restrict__ bias2, const float* __restrict__ Q,
    float* __restrict__ out)
{
    const int lane = threadIdx.x & 63;
    const int wave = blockIdx.x * 4 + (threadIdx.x >> 6);
    const int row0 = wave * 16;
    const int m  = lane & 15;
    const int kg = lane >> 4;

    const ushort* ap = tmp + (size_t)(row0 + m) * 128 + kg * 8;

    f32x4 acc[NF_O];
    #pragma unroll
    for (int f = 0; f < NF_O; ++f) acc[f] = (f32x4){0.f, 0.f, 0.f, 0.f};

    #pragma unroll
    for (int ks = 0; ks < KS; ++ks) {
        short8 af = *(const short8*)(ap + ks * 32);
        const short8* wrow = (const short8*)wtp2 + ks * NF_O * 64 + lane;
        #pragma unroll
        for (int f = 0; f < NF_O; ++f)
            acc[f] = __builtin_amdgcn_mfma_f32_16x16x32_bf16(af, wrow[f * 64], acc[f], 0, 0, 0);
    }

    #pragma unroll
    for (int f = 0; f < NF_O; ++f) {
        const int col = f * 16 + m;
        const float bb = bias2[col];
        #pragma unroll
        for (int r = 0; r < 4; ++r) {
            const int row = row0 + kg * 4 + r;
            out[(size_t)row * 128 + col] = acc[f][r] + bb + Q[(size_t)row * 128 + col];
        }
    }
}

// ---------------------------------------------------------------------------
extern "C" void kernel_launch(void* const* d_in, const int* in_sizes, int n_in,
                              void* d_out, int out_size, void* d_ws, size_t ws_size,
                              hipStream_t stream) {
    const float* Q     = (const float*)d_in[0];
    const float* Wv    = (const float*)d_in[1];
    const float* bv    = (const float*)d_in[2];
    const float* Woff  = (const float*)d_in[3];
    const float* boff  = (const float*)d_in[4];
    const float* Wattn = (const float*)d_in[5];
    const float* battn = (const float*)d_in[6];
    const float* Wout1 = (const float*)d_in[7];
    const float* bout1 = (const float*)d_in[8];
    const float* Wout2 = (const float*)d_in[9];
    const float* bout2 = (const float*)d_in[10];
    float* out = (float*)d_out;

    // Workspace: proj_s f32[BN][96] | biasp[224] | b12[128] |
    //            proj_v bf16[BN][128] | tmp bf16[BN][128] | wtp | wtp2
    float*  proj_s = (float*)d_ws;
    float*  biasp  = proj_s + (size_t)BN * SC;
    float*  bias2  = biasp + 224;
    ushort* proj_v = (ushort*)(bias2 + 128);
    ushort* tmp    = proj_v + (size_t)BN * 128;
    ushort* wtp    = tmp + (size_t)BN * 128;
    ushort* wtp2   = wtp + (size_t)KS * NF_P * 64 * 8;

    constexpr int prep_n = KS * NF_P * 64 + KS * NF_O * 64 + 224 + 128; // 5984
    vsa_k_prep<<<(prep_n + 255) / 256, 256, 0, stream>>>(
        Wv, bv, Woff, boff, Wattn, battn, Wout1, bout1, Wout2, bout2,
        wtp, wtp2, biasp, bias2);
    vsa_k_proj<<<BN / 64, 256, 0, stream>>>(Q, wtp, biasp, proj_v, proj_s);
    vsa_k_sample<<<(BN * H) / 4, 256, 0, stream>>>(proj_v, proj_s, tmp);
    vsa_k_out<<<BN / 64, 256, 0, stream>>>(tmp, wtp2, bias2, Q, out);
}